// Round 2
// baseline (2741.588 us; speedup 1.0000x reference)
//
#include <hip/hip_runtime.h>
#include <hip/hip_fp16.h>

#define NB 8
#define NC 512
#define NK 128   // key_dim C2
#define NH 128
#define NW 128
#define NHW 16384

typedef unsigned short u16;
typedef unsigned int u32;

__device__ __forceinline__ float h2f(u16 u) {
    return __half2float(__ushort_as_half(u));
}
__device__ __forceinline__ u16 f2h(float f) {
    return __half_as_ushort(__float2half(f));
}

// ---------------- transpose last two dims of [planes][128][128] (16-bit elems) ----------------
__global__ __launch_bounds__(256) void transpose_hw_kernel(const u16* __restrict__ in,
                                                           u16* __restrict__ out) {
    __shared__ u16 ts[32][33];
    int plane = blockIdx.y;
    int tile  = blockIdx.x;
    int h0 = (tile >> 2) * 32, w0 = (tile & 3) * 32;
    const u16* ip = in + (size_t)plane * NHW;
    u16* op = out + (size_t)plane * NHW;
    int r  = threadIdx.x >> 3;
    int c4 = (threadIdx.x & 7) * 4;
    ushort4 v = *(const ushort4*)(ip + (h0 + r) * NW + w0 + c4);
    ts[r][c4 + 0] = v.x; ts[r][c4 + 1] = v.y; ts[r][c4 + 2] = v.z; ts[r][c4 + 3] = v.w;
    __syncthreads();
    ushort4 o;
    o.x = ts[c4 + 0][r]; o.y = ts[c4 + 1][r]; o.z = ts[c4 + 2][r]; o.w = ts[c4 + 3][r];
    *(ushort4*)(op + (w0 + r) * NH + h0 + c4) = o;
}

// ---------------- 1x1 conv projection: out[b,oc,p] = sum_c x[b,c,p]*w[oc,c] + bias[oc]
// x fp32, w/bias fp32, out fp16
__global__ __launch_bounds__(256) void proj_kernel(const float* __restrict__ x,
                                                   const float* __restrict__ w,
                                                   const float* __restrict__ bias,
                                                   u16* __restrict__ out) {
    __shared__ float xs[32][68];
    __shared__ float wsT[32][132];
    int b  = blockIdx.y;
    int p0 = blockIdx.x * 64;
    int tid = threadIdx.x;
    int pi = tid & 15;   // pixel group: pixels p0 + pi*4 .. +3
    int oi = tid >> 4;   // oc group: oc = oi*8 .. +7
    float acc[8][4] = {};
    for (int c0 = 0; c0 < NC; c0 += 32) {
        {   // stage x chunk [32 c][64 px]
            int row = tid >> 3, off = (tid & 7) * 8;
            const float* src = x + (size_t)(b * NC + c0 + row) * NHW + p0 + off;
            float4 v0 = *(const float4*)src;
            float4 v1 = *(const float4*)(src + 4);
            *(float4*)&xs[row][off] = v0;
            *(float4*)&xs[row][off + 4] = v1;
        }
        {   // stage weights transposed: wsT[i][oc]
            int oc = tid >> 1, i0 = (tid & 1) * 16;
            const float* srcw = w + oc * NC + c0 + i0;
            float tmp[16];
            *(float4*)&tmp[0]  = *(const float4*)(srcw);
            *(float4*)&tmp[4]  = *(const float4*)(srcw + 4);
            *(float4*)&tmp[8]  = *(const float4*)(srcw + 8);
            *(float4*)&tmp[12] = *(const float4*)(srcw + 12);
#pragma unroll
            for (int j = 0; j < 16; j++) wsT[i0 + j][oc] = tmp[j];
        }
        __syncthreads();
        for (int i = 0; i < 32; i++) {
            float4 xv = *(const float4*)&xs[i][pi * 4];
            float4 wv0 = *(const float4*)&wsT[i][oi * 8];
            float4 wv1 = *(const float4*)&wsT[i][oi * 8 + 4];
            const float wf[8] = {wv0.x, wv0.y, wv0.z, wv0.w, wv1.x, wv1.y, wv1.z, wv1.w};
#pragma unroll
            for (int j = 0; j < 8; j++) {
                acc[j][0] += wf[j] * xv.x;
                acc[j][1] += wf[j] * xv.y;
                acc[j][2] += wf[j] * xv.z;
                acc[j][3] += wf[j] * xv.w;
            }
        }
        __syncthreads();
    }
#pragma unroll
    for (int j = 0; j < 8; j++) {
        float bj = bias[oi * 8 + j];
        ushort4 o;
        o.x = f2h(acc[j][0] + bj);
        o.y = f2h(acc[j][1] + bj);
        o.z = f2h(acc[j][2] + bj);
        o.w = f2h(acc[j][3] + bj);
        *(ushort4*)(out + (size_t)(b * NK + oi * 8 + j) * NHW + p0 + pi * 4) = o;
    }
}

// ---------------- generic axis attention ----------------
// Q,K: fp16, laid out so position j is contiguous (std for W-pass, transposed for H-pass).
// V = x (fp32), accessed with compile-time stride VJS along j.
// per (b, r): E[i][j] = sum_c K[c][i]*Q[c][j]; A = softmax_j(E); O[c][i] = sum_j A[i][j]*V[c][j]
// OADD=0: O stored at (b,c) plane offset r*128 + i (W-pass, coalesced write)
// OADD=1: O added  at (b,c) plane offset i*128 + r (H-pass, scattered RMW)
template <int VJS, int OADD>
__global__ __launch_bounds__(256) void attn_kernel(const u16* __restrict__ Qp,
                                                   const u16* __restrict__ Kp,
                                                   const float* __restrict__ Vp,
                                                   float* __restrict__ Op) {
    __shared__ u16 Ks[128 * 136];
    __shared__ u16 Qs[128 * 136];
    __shared__ float Es[128 * 132];
    __shared__ float xt[32 * 132];
    __shared__ float red[256];

    int r = blockIdx.x, b = blockIdx.y;
    int tid = threadIdx.x;
    const size_t qkbase = (size_t)b * NK * NHW + (size_t)r * 128;

    // stage K,Q (fp16): [128 c][128 pos], contiguous along pos
#pragma unroll
    for (int rr = 0; rr < 8; rr++) {
        int e = rr * 256 + tid;
        int c = e >> 4;
        int j0 = (e & 15) * 8;
        uint4 vq = *(const uint4*)(Qp + qkbase + (size_t)c * NHW + j0);
        uint4 vk = *(const uint4*)(Kp + qkbase + (size_t)c * NHW + j0);
        *(uint4*)&Qs[c * 136 + j0] = vq;
        *(uint4*)&Ks[c * 136 + j0] = vk;
    }
    __syncthreads();

    // ---- E = K^T Q ----
    {
        int ii = tid >> 4, jj = tid & 15;
        int i0 = ii * 8, j0 = jj * 8;
        float facc[8][8] = {};
        for (int c = 0; c < 128; c++) {
            uint4 kv = *(const uint4*)&Ks[c * 136 + i0];
            uint4 qv = *(const uint4*)&Qs[c * 136 + j0];
            u16* kp = (u16*)&kv;
            u16* qp = (u16*)&qv;
            float kf[8], qf[8];
#pragma unroll
            for (int a = 0; a < 8; a++) { kf[a] = h2f(kp[a]); qf[a] = h2f(qp[a]); }
#pragma unroll
            for (int a = 0; a < 8; a++)
#pragma unroll
                for (int bb = 0; bb < 8; bb++)
                    facc[a][bb] += kf[a] * qf[bb];
        }
#pragma unroll
        for (int a = 0; a < 8; a++) {
            *(float4*)&Es[(i0 + a) * 132 + j0]     = make_float4(facc[a][0], facc[a][1], facc[a][2], facc[a][3]);
            *(float4*)&Es[(i0 + a) * 132 + j0 + 4] = make_float4(facc[a][4], facc[a][5], facc[a][6], facc[a][7]);
        }
    }
    __syncthreads();

    // ---- softmax over j (rows of Es) ----
    {
        int row = tid & 127;
        float* erow = &Es[row * 132 + (tid >> 7) * 64];
        float m = -1e30f;
        for (int j2 = 0; j2 < 64; j2++) m = fmaxf(m, erow[j2]);
        red[tid] = m;
        __syncthreads();
        m = fmaxf(red[row], red[row + 128]);
        __syncthreads();
        float s = 0.f;
        for (int j2 = 0; j2 < 64; j2++) {
            float e = __expf(erow[j2] - m);
            erow[j2] = e;
            s += e;
        }
        red[tid] = s;
        __syncthreads();
        float inv = 1.0f / (red[row] + red[row + 128]);
        for (int j2 = 0; j2 < 64; j2++) erow[j2] *= inv;
    }
    __syncthreads();

    // ---- O[c][i] = sum_j A[i][j] * V[c][j], c tiled by 32 ----
    {
        int ci = tid >> 4;   // 0..15  -> c pair (ci*2, ci*2+1)
        int iw = tid & 15;   // i = iw + k8*16
        for (int c0 = 0; c0 < NC; c0 += 32) {
            // stage V tile [32 c][128 j]
            {
                int cc = tid >> 3;
                int j0 = (tid & 7) * 16;
                const float* vsrc = Vp + (size_t)(b * NC + c0 + cc) * NHW + (size_t)r * (VJS == 1 ? 128 : 1);
                if (VJS == 1) {
#pragma unroll
                    for (int q4 = 0; q4 < 4; q4++)
                        *(float4*)&xt[cc * 132 + j0 + q4 * 4] = *(const float4*)(vsrc + j0 + q4 * 4);
                } else {
#pragma unroll
                    for (int jj = 0; jj < 16; jj++)
                        xt[cc * 132 + j0 + jj] = vsrc[(size_t)(j0 + jj) * VJS];
                }
            }
            __syncthreads();
            float acc0[8] = {}, acc1[8] = {};
            for (int j = 0; j < 128; j += 4) {
                float4 xv0 = *(const float4*)&xt[(ci * 2 + 0) * 132 + j];
                float4 xv1 = *(const float4*)&xt[(ci * 2 + 1) * 132 + j];
#pragma unroll
                for (int k8 = 0; k8 < 8; k8++) {
                    const float4 av = *(const float4*)&Es[(iw + k8 * 16) * 132 + j];
                    acc0[k8] += av.x * xv0.x + av.y * xv0.y + av.z * xv0.z + av.w * xv0.w;
                    acc1[k8] += av.x * xv1.x + av.y * xv1.y + av.z * xv1.z + av.w * xv1.w;
                }
            }
            size_t pbase0 = (size_t)(b * NC + c0 + ci * 2 + 0) * NHW;
            size_t pbase1 = pbase0 + NHW;
#pragma unroll
            for (int k8 = 0; k8 < 8; k8++) {
                int i = iw + k8 * 16;
                if (OADD == 0) {
                    Op[pbase0 + (size_t)r * 128 + i] = acc0[k8];
                    Op[pbase1 + (size_t)r * 128 + i] = acc1[k8];
                } else {
                    Op[pbase0 + (size_t)i * 128 + r] += acc0[k8];
                    Op[pbase1 + (size_t)i * 128 + r] += acc1[k8];
                }
            }
            __syncthreads();
        }
    }
}

extern "C" void kernel_launch(void* const* d_in, const int* in_sizes, int n_in,
                              void* d_out, int out_size, void* d_ws, size_t ws_size,
                              hipStream_t stream) {
    const float* x  = (const float*)d_in[0];
    const float* wq = (const float*)d_in[1];
    const float* bq = (const float*)d_in[2];
    const float* wk = (const float*)d_in[3];
    const float* bk = (const float*)d_in[4];
    float* out = (float*)d_out;

    const size_t QK = (size_t)NB * NK * NHW;   // 16,777,216 elems (fp16 -> 32 MiB each)
    u16* q_std = (u16*)d_ws;
    u16* k_std = q_std + QK;
    u16* q_tr  = k_std + QK;
    u16* k_tr  = q_tr + QK;   // total 128 MiB

    dim3 blk(256);

    // 1. projections (fp16 outputs, std layout [b][c2][h][w])
    proj_kernel<<<dim3(NHW / 64, NB), blk, 0, stream>>>(x, wq, bq, q_std);
    proj_kernel<<<dim3(NHW / 64, NB), blk, 0, stream>>>(x, wk, bk, k_std);
    // 2. q,k -> transposed [b][c2][w][h]
    transpose_hw_kernel<<<dim3(16, NB * NK), blk, 0, stream>>>(q_std, q_tr);
    transpose_hw_kernel<<<dim3(16, NB * NK), blk, 0, stream>>>(k_std, k_tr);
    // 3. W-attention -> out (pure write, overwrites poison)
    attn_kernel<1, 0><<<dim3(128, NB), blk, 0, stream>>>(q_std, k_std, x, out);
    // 4. H-attention -> out += (transposed scatter-add)
    attn_kernel<128, 1><<<dim3(128, NB), blk, 0, stream>>>(q_tr, k_tr, x, out);
}

// Round 3
// 574.257 us; speedup vs baseline: 4.7741x; 4.7741x over previous
//
#include <hip/hip_runtime.h>
#include <hip/hip_fp16.h>

#define NB 8
#define NC 512
#define NK 128   // key_dim C2
#define NP 128   // positions per attention row (H = W = 128)
#define NHW 16384

typedef unsigned short u16;
typedef unsigned int u32;
typedef float f32x4 __attribute__((ext_vector_type(4)));
typedef _Float16 f16x8 __attribute__((ext_vector_type(8)));

__device__ __forceinline__ u16 f2h(float f) { return __half_as_ushort(__float2half(f)); }
__device__ __forceinline__ float h2f(u16 u) { return __half2float(__ushort_as_half(u)); }

// ---------------- x fp32 [plane][h][w] -> xt fp16 [plane][w][h] ----------------
__global__ __launch_bounds__(256) void convtr_kernel(const float* __restrict__ x,
                                                     u16* __restrict__ xt) {
    __shared__ u16 ts[32][36];
    int plane = blockIdx.y;
    int tile  = blockIdx.x;
    int h0 = (tile >> 2) * 32, w0 = (tile & 3) * 32;
    const float* ip = x + (size_t)plane * NHW;
    u16* op = xt + (size_t)plane * NHW;
    int r  = threadIdx.x >> 3;
    int c4 = (threadIdx.x & 7) * 4;
    float4 v = *(const float4*)(ip + (h0 + r) * NP + w0 + c4);
    ts[r][c4 + 0] = f2h(v.x); ts[r][c4 + 1] = f2h(v.y);
    ts[r][c4 + 2] = f2h(v.z); ts[r][c4 + 3] = f2h(v.w);
    __syncthreads();
    ushort4 o;
    o.x = ts[c4 + 0][r]; o.y = ts[c4 + 1][r]; o.z = ts[c4 + 2][r]; o.w = ts[c4 + 3][r];
    *(ushort4*)(op + (w0 + r) * NP + h0 + c4) = o;
}

// ---------------- fused q+k projection via MFMA ----------------
// q[b][p][c2], k[b][p][c2] fp16 (pixel-major).  Tile: 128 p x 256 oc, K=512.
// LDS stores A (x-transposed) and B (weights) with c-pair interleaved k-order
// (same permutation on both operands -> contraction unchanged).
__global__ __launch_bounds__(256) void proj_kernel(const float* __restrict__ x,
                                                   const float* __restrict__ wq,
                                                   const float* __restrict__ bq,
                                                   const float* __restrict__ wk,
                                                   const float* __restrict__ bk,
                                                   u16* __restrict__ q,
                                                   u16* __restrict__ k) {
    __shared__ __align__(16) u16 Xt2[128 * 40];
    __shared__ __align__(16) u16 Wl[256 * 40];
    int b  = blockIdx.y;
    int p0 = blockIdx.x * 128;
    int tid = threadIdx.x;
    int lane = tid & 63, w = tid >> 6;
    int ln = lane & 15, g = lane >> 4;
    int wm = w >> 1, wn = w & 1;

    f32x4 acc[4][8];
#pragma unroll
    for (int mf = 0; mf < 4; mf++)
#pragma unroll
        for (int nf = 0; nf < 8; nf++) acc[mf][nf] = 0.0f;

    for (int c0 = 0; c0 < NC; c0 += 32) {
        // stage X^T tile: thread handles c-pair (pairIdx, pairIdx+16), 8 pixels
        {
            int pairIdx = tid >> 4;
            int p16 = (tid & 15) * 8;
            const float* xa = x + ((size_t)(b * NC + c0 + pairIdx)) * NHW + p0 + p16;
            const float* xb = xa + (size_t)16 * NHW;
            float av[8], bv[8];
            *(float4*)&av[0] = *(const float4*)(xa);
            *(float4*)&av[4] = *(const float4*)(xa + 4);
            *(float4*)&bv[0] = *(const float4*)(xb);
            *(float4*)&bv[4] = *(const float4*)(xb + 4);
#pragma unroll
            for (int j = 0; j < 8; j++) {
                ushort2 pk;
                pk.x = f2h(av[j]);
                pk.y = f2h(bv[j]);
                *(ushort2*)&Xt2[(p16 + j) * 40 + 2 * pairIdx] = pk;
            }
        }
        // stage W tile: thread = one oc row (0..127 -> wq, 128..255 -> wk)
        {
            const float* srcw = (tid < 128 ? wq : wk) + (size_t)(tid & 127) * NC + c0;
            float buf[32];
#pragma unroll
            for (int q4 = 0; q4 < 8; q4++)
                *(float4*)&buf[q4 * 4] = *(const float4*)(srcw + q4 * 4);
            u16 hb[32];
#pragma unroll
            for (int i = 0; i < 16; i++) {
                hb[2 * i]     = f2h(buf[i]);
                hb[2 * i + 1] = f2h(buf[16 + i]);
            }
#pragma unroll
            for (int e = 0; e < 4; e++)
                *(uint4*)&Wl[tid * 40 + e * 8] = *(uint4*)&hb[e * 8];
        }
        __syncthreads();
        f16x8 af[4], bf[8];
#pragma unroll
        for (int mf = 0; mf < 4; mf++)
            af[mf] = *(const f16x8*)&Xt2[(wm * 64 + mf * 16 + ln) * 40 + g * 8];
#pragma unroll
        for (int nf = 0; nf < 8; nf++)
            bf[nf] = *(const f16x8*)&Wl[(wn * 128 + nf * 16 + ln) * 40 + g * 8];
#pragma unroll
        for (int mf = 0; mf < 4; mf++)
#pragma unroll
            for (int nf = 0; nf < 8; nf++)
                acc[mf][nf] = __builtin_amdgcn_mfma_f32_16x16x32_f16(af[mf], bf[nf], acc[mf][nf], 0, 0, 0);
        __syncthreads();
    }
    // epilogue: bias + store fp16 pixel-major
#pragma unroll
    for (int nf = 0; nf < 8; nf++) {
        int oc = wn * 128 + nf * 16 + ln;
        float bias = (oc < 128) ? bq[oc] : bk[oc - 128];
        u16* dst = (oc < 128) ? q : k;
        int occ = oc & 127;
#pragma unroll
        for (int mf = 0; mf < 4; mf++)
#pragma unroll
            for (int rg = 0; rg < 4; rg++) {
                int p = p0 + wm * 64 + mf * 16 + g * 4 + rg;
                dst[((size_t)b * NHW + p) * NK + occ] = f2h(acc[mf][nf][rg] + bias);
            }
    }
}

// ---------------- axis attention via MFMA ----------------
// TR=0 (W-pass): r=h, Q/K rows contiguous, V = x fp32, out = float*
// TR=1 (H-pass): r=w, Q/K rows strided, V = xt fp16, out = oht fp16
// E^T[j][i] = sum_c Q[j][c]*K[i][c]; softmax over j; O[c][i] = sum_j A[i][j]V[c][j]
template <int TR>
__global__ __launch_bounds__(256) void attn_kernel(const u16* __restrict__ q,
                                                   const u16* __restrict__ k,
                                                   const void* __restrict__ vsrc,
                                                   void* __restrict__ osrc) {
    __shared__ __align__(16) u16 smem[2 * 128 * 136];
    __shared__ float redmax[256];
    __shared__ float redsum[256];
    u16* Ks = smem;                 // later reused as A_lds
    u16* Qs = smem + 128 * 136;     // later reused as Vlds
    u16* Al = smem;
    u16* Vl = smem + 128 * 136;

    int r = blockIdx.x, b = blockIdx.y;
    int tid = threadIdx.x;
    int lane = tid & 63, w = tid >> 6;
    int ln = lane & 15, g = lane >> 4;

    const size_t base = TR ? ((size_t)b * NHW + r) * NK : ((size_t)b * NHW + (size_t)r * NP) * NK;
    const int qrs = TR ? NP * NK : NK;

    // stage Q,K position-major [j][c]
    {
        int j = tid >> 1, hf = tid & 1;
        const u16* qp2 = q + base + (size_t)j * qrs + hf * 64;
        const u16* kp2 = k + base + (size_t)j * qrs + hf * 64;
#pragma unroll
        for (int e = 0; e < 8; e++) {
            *(uint4*)&Qs[j * 136 + hf * 64 + e * 8] = *(const uint4*)(qp2 + e * 8);
            *(uint4*)&Ks[j * 136 + hf * 64 + e * 8] = *(const uint4*)(kp2 + e * 8);
        }
    }
    __syncthreads();

    // ---- E^T via MFMA: wave tile (wj*64 j) x (wi*64 i) ----
    int wj = w >> 1, wi = w & 1;
    f32x4 e[4][4];   // [mf=j][nf=i]
#pragma unroll
    for (int mf = 0; mf < 4; mf++)
#pragma unroll
        for (int nf = 0; nf < 4; nf++) e[mf][nf] = 0.0f;
#pragma unroll
    for (int ks = 0; ks < 4; ks++) {
        f16x8 qa[4], kb[4];
#pragma unroll
        for (int mf = 0; mf < 4; mf++)
            qa[mf] = *(const f16x8*)&Qs[(wj * 64 + mf * 16 + ln) * 136 + ks * 32 + g * 8];
#pragma unroll
        for (int nf = 0; nf < 4; nf++)
            kb[nf] = *(const f16x8*)&Ks[(wi * 64 + nf * 16 + ln) * 136 + ks * 32 + g * 8];
#pragma unroll
        for (int mf = 0; mf < 4; mf++)
#pragma unroll
            for (int nf = 0; nf < 4; nf++)
                e[mf][nf] = __builtin_amdgcn_mfma_f32_16x16x32_f16(qa[mf], kb[nf], e[mf][nf], 0, 0, 0);
    }

    // ---- softmax over j (m-dim): per-lane partials + shfl + cross-wave LDS ----
    float pm[4];
#pragma unroll
    for (int nf = 0; nf < 4; nf++) {
        pm[nf] = -3.0e38f;
#pragma unroll
        for (int mf = 0; mf < 4; mf++)
#pragma unroll
            for (int rg = 0; rg < 4; rg++) pm[nf] = fmaxf(pm[nf], e[mf][nf][rg]);
        pm[nf] = fmaxf(pm[nf], __shfl_xor(pm[nf], 16));
        pm[nf] = fmaxf(pm[nf], __shfl_xor(pm[nf], 32));
    }
    if (g == 0) {
#pragma unroll
        for (int nf = 0; nf < 4; nf++) redmax[wj * 128 + wi * 64 + nf * 16 + ln] = pm[nf];
    }
    __syncthreads();
    float fm[4];
#pragma unroll
    for (int nf = 0; nf < 4; nf++) {
        int i = wi * 64 + nf * 16 + ln;
        fm[nf] = fmaxf(redmax[i], redmax[128 + i]);
    }
    float ps[4] = {0.f, 0.f, 0.f, 0.f};
#pragma unroll
    for (int mf = 0; mf < 4; mf++)
#pragma unroll
        for (int nf = 0; nf < 4; nf++)
#pragma unroll
            for (int rg = 0; rg < 4; rg++) {
                float v = __expf(e[mf][nf][rg] - fm[nf]);
                e[mf][nf][rg] = v;
                ps[nf] += v;
            }
#pragma unroll
    for (int nf = 0; nf < 4; nf++) {
        ps[nf] += __shfl_xor(ps[nf], 16);
        ps[nf] += __shfl_xor(ps[nf], 32);
    }
    if (g == 0) {
#pragma unroll
        for (int nf = 0; nf < 4; nf++) redsum[wj * 128 + wi * 64 + nf * 16 + ln] = ps[nf];
    }
    __syncthreads();
    float ivs[4];
#pragma unroll
    for (int nf = 0; nf < 4; nf++) {
        int i = wi * 64 + nf * 16 + ln;
        ivs[nf] = 1.0f / (redsum[i] + redsum[128 + i]);
    }
    // pack A fp16 into A_lds[i][j]  (Ks region; all K/Q reads completed pre-sync)
#pragma unroll
    for (int mf = 0; mf < 4; mf++)
#pragma unroll
        for (int nf = 0; nf < 4; nf++) {
            ushort4 pk;
            pk.x = f2h(e[mf][nf][0] * ivs[nf]);
            pk.y = f2h(e[mf][nf][1] * ivs[nf]);
            pk.z = f2h(e[mf][nf][2] * ivs[nf]);
            pk.w = f2h(e[mf][nf][3] * ivs[nf]);
            *(ushort4*)&Al[(wi * 64 + nf * 16 + ln) * 136 + wj * 64 + mf * 16 + g * 4] = pk;
        }
    __syncthreads();

    // ---- PV: O[c][i] = sum_j V[c][j] * A[i][j], c in tiles of 64 ----
    int wc = w >> 1, wi2 = w & 1;
    f16x8 bfr[4][4];  // [nf2][js] hoisted A-rows
#pragma unroll
    for (int nf2 = 0; nf2 < 4; nf2++)
#pragma unroll
        for (int js = 0; js < 4; js++)
            bfr[nf2][js] = *(const f16x8*)&Al[(wi2 * 64 + nf2 * 16 + ln) * 136 + js * 32 + g * 8];

    for (int c0 = 0; c0 < NC; c0 += 64) {
        // stage V tile [64 c][128 j]
        {
            int cc = tid >> 2, ch = (tid & 3) * 32;
            if (TR == 0) {
                const float* vp = (const float*)vsrc + ((size_t)(b * NC + c0 + cc)) * NHW + (size_t)r * NP + ch;
                u16 tmp[32];
#pragma unroll
                for (int q4 = 0; q4 < 8; q4++) {
                    float4 vv = *(const float4*)(vp + q4 * 4);
                    tmp[q4 * 4 + 0] = f2h(vv.x);
                    tmp[q4 * 4 + 1] = f2h(vv.y);
                    tmp[q4 * 4 + 2] = f2h(vv.z);
                    tmp[q4 * 4 + 3] = f2h(vv.w);
                }
#pragma unroll
                for (int q8 = 0; q8 < 4; q8++)
                    *(uint4*)&Vl[cc * 136 + ch + q8 * 8] = *(uint4*)&tmp[q8 * 8];
            } else {
                const u16* vp = (const u16*)vsrc + ((size_t)(b * NC + c0 + cc)) * NHW + (size_t)r * NP + ch;
#pragma unroll
                for (int q8 = 0; q8 < 4; q8++)
                    *(uint4*)&Vl[cc * 136 + ch + q8 * 8] = *(const uint4*)(vp + q8 * 8);
            }
        }
        __syncthreads();
        f32x4 o[2][4];
#pragma unroll
        for (int mf2 = 0; mf2 < 2; mf2++)
#pragma unroll
            for (int nf2 = 0; nf2 < 4; nf2++) o[mf2][nf2] = 0.0f;
#pragma unroll
        for (int js = 0; js < 4; js++) {
            f16x8 va[2];
#pragma unroll
            for (int mf2 = 0; mf2 < 2; mf2++)
                va[mf2] = *(const f16x8*)&Vl[(wc * 32 + mf2 * 16 + ln) * 136 + js * 32 + g * 8];
#pragma unroll
            for (int mf2 = 0; mf2 < 2; mf2++)
#pragma unroll
                for (int nf2 = 0; nf2 < 4; nf2++)
                    o[mf2][nf2] = __builtin_amdgcn_mfma_f32_16x16x32_f16(va[mf2], bfr[nf2][js], o[mf2][nf2], 0, 0, 0);
        }
        // store
#pragma unroll
        for (int mf2 = 0; mf2 < 2; mf2++)
#pragma unroll
            for (int nf2 = 0; nf2 < 4; nf2++)
#pragma unroll
                for (int rg = 0; rg < 4; rg++) {
                    int ci = c0 + wc * 32 + mf2 * 16 + g * 4 + rg;
                    int ii = wi2 * 64 + nf2 * 16 + ln;
                    size_t oa = ((size_t)(b * NC + ci)) * NHW + (size_t)r * NP + ii;
                    if (TR == 0) ((float*)osrc)[oa] = o[mf2][nf2][rg];
                    else         ((u16*)osrc)[oa] = f2h(o[mf2][nf2][rg]);
                }
        __syncthreads();
    }
}

// ---------------- out[plane][h][w] += oht[plane][w][h] (fp16 -> fp32 RMW) ----------------
__global__ __launch_bounds__(256) void addtr_kernel(const u16* __restrict__ oht,
                                                    float* __restrict__ out) {
    __shared__ u16 ts[32][36];
    int plane = blockIdx.y;
    int tile  = blockIdx.x;
    int h0 = (tile >> 2) * 32, w0 = (tile & 3) * 32;
    int r  = threadIdx.x >> 3;
    int c4 = (threadIdx.x & 7) * 4;
    ushort4 v = *(const ushort4*)(oht + (size_t)plane * NHW + (w0 + r) * NP + h0 + c4);
    ts[r][c4 + 0] = v.x; ts[r][c4 + 1] = v.y; ts[r][c4 + 2] = v.z; ts[r][c4 + 3] = v.w;
    __syncthreads();
    float* dst = out + (size_t)plane * NHW + (h0 + r) * NP + w0 + c4;
    float4 cur = *(const float4*)dst;
    cur.x += h2f(ts[c4 + 0][r]);
    cur.y += h2f(ts[c4 + 1][r]);
    cur.z += h2f(ts[c4 + 2][r]);
    cur.w += h2f(ts[c4 + 3][r]);
    *(float4*)dst = cur;
}

extern "C" void kernel_launch(void* const* d_in, const int* in_sizes, int n_in,
                              void* d_out, int out_size, void* d_ws, size_t ws_size,
                              hipStream_t stream) {
    const float* x  = (const float*)d_in[0];
    const float* wq = (const float*)d_in[1];
    const float* bq = (const float*)d_in[2];
    const float* wk = (const float*)d_in[3];
    const float* bk = (const float*)d_in[4];
    float* out = (float*)d_out;

    const size_t QKE = (size_t)NB * NHW * NK;  // 16,777,216 elems
    const size_t XE  = (size_t)NB * NC * NHW;  // 67,108,864 elems
    u16* q   = (u16*)d_ws;
    u16* k   = q + QKE;
    u16* xt  = k + QKE;
    u16* oht = xt + XE;   // total 2*QKE + 2*XE = 167.8M u16 = 320 MiB

    dim3 blk(256);

    // 1. x -> xt fp16 transposed [b][c][w][h]
    convtr_kernel<<<dim3(16, NB * NC), blk, 0, stream>>>(x, xt);
    // 2. fused q,k projection (MFMA), pixel-major fp16
    proj_kernel<<<dim3(NHW / 128, NB), blk, 0, stream>>>(x, wq, bq, wk, bk, q, k);
    // 3. H-attention -> oht fp16 [b][c][w][h]
    attn_kernel<1><<<dim3(NP, NB), blk, 0, stream>>>(q, k, (const void*)xt, (void*)oht);
    // 4. W-attention -> out fp32 (pure write, overwrites poison)
    attn_kernel<0><<<dim3(NP, NB), blk, 0, stream>>>(q, k, (const void*)x, (void*)out);
    // 5. out += transpose(oht)
    addtr_kernel<<<dim3(16, NB * NC), blk, 0, stream>>>(oht, out);
}